// Round 1
// baseline (17.243 us; speedup 1.0000x reference)
//
#include <hip/hip_runtime.h>

// Problem: N=4096 rows, D=64 fp32. Zero any row that exactly equals an earlier row.
#define NROWS 4096
#define DCOLS 64

__device__ __forceinline__ unsigned long long mix64(unsigned long long z) {
    z += 0x9E3779B97F4A7C15ULL;
    z = (z ^ (z >> 30)) * 0xBF58476D1CE4E5B9ULL;
    z = (z ^ (z >> 27)) * 0x94D049BB133111EBULL;
    return z ^ (z >> 31);
}

// Kernel A: one 64-lane wave per row -> 64-bit position-sensitive hash.
// 256-thread blocks = 4 rows/block. Coalesced: lane k reads x[row*64+k].
__global__ void hash_rows_kernel(const float* __restrict__ x,
                                 unsigned long long* __restrict__ h) {
    const int wave = threadIdx.x >> 6;          // 0..3
    const int lane = threadIdx.x & 63;
    const int row  = blockIdx.x * 4 + wave;
    if (row >= NROWS) return;

    float v = x[row * DCOLS + lane];
    unsigned int bits = __float_as_uint(v);
    if (v == 0.0f) bits = 0u;                   // canonicalize -0.0 == +0.0 (ref uses float ==)

    unsigned long long m =
        mix64((unsigned long long)bits +
              (unsigned long long)lane * 0xD6E8FEB86659FD93ULL);

    // XOR-reduce across the 64-lane wave (position baked in via `lane` above)
    #pragma unroll
    for (int off = 32; off > 0; off >>= 1)
        m ^= __shfl_xor(m, off, 64);

    if (lane == 0) h[row] = m;
}

// Kernel B: one block per row i. Scan hashes of rows j<i; on hash match do the
// exact float== compare (decides correctness; NaN rows correctly never match).
__global__ void __launch_bounds__(256)
dedup_mask_kernel(const float* __restrict__ x,
                  const unsigned long long* __restrict__ h,
                  float* __restrict__ out) {
    const int i = blockIdx.x;
    const int t = threadIdx.x;

    __shared__ float row[DCOLS];
    __shared__ int dup;

    if (t < DCOLS) row[t] = x[i * DCOLS + t];
    if (t == 0) dup = 0;
    __syncthreads();

    const unsigned long long hi = h[i];
    for (int j = t; j < i; j += 256) {          // coalesced 8B hash loads
        if (h[j] == hi) {
            bool eq = true;
            const float* xj = x + j * DCOLS;
            #pragma unroll
            for (int k = 0; k < DCOLS; ++k)
                eq = eq && (xj[k] == row[k]);   // float ==: handles ±0 and NaN per reference
            if (eq) atomicOr(&dup, 1);
        }
    }
    __syncthreads();

    if (t < DCOLS)
        out[i * DCOLS + t] = dup ? 0.0f : row[t];
}

extern "C" void kernel_launch(void* const* d_in, const int* in_sizes, int n_in,
                              void* d_out, int out_size, void* d_ws, size_t ws_size,
                              hipStream_t stream) {
    const float* x = (const float*)d_in[0];
    float* out = (float*)d_out;
    unsigned long long* h = (unsigned long long*)d_ws;   // 4096 * 8B = 32 KiB scratch

    hash_rows_kernel<<<NROWS / 4, 256, 0, stream>>>(x, h);
    dedup_mask_kernel<<<NROWS, 256, 0, stream>>>(x, h, out);
}